// Round 1
// baseline (381.980 us; speedup 1.0000x reference)
//
#include <hip/hip_runtime.h>

// KVMN forward: o[b,s,:] = sum_m p[b,s,m] * value_table[lvm[b,s,m],:]
// p = softmax-like masked normalization of u = <hs[b,s], key_table[wseq[b,m]]>/sqrt(H)
//
// B=4 S=512 M=128 H=768. One block per (b,s), 256 threads (4 waves).

constexpr int B = 4, S = 512, M = 128, H = 768;

__global__ __launch_bounds__(256) void kvmn_kernel(
    const int*   __restrict__ word_seq,      // [B, M]
    const float* __restrict__ hidden_state,  // [B, S, H]
    const int*   __restrict__ lvm,           // [B, S, M]
    const float* __restrict__ mask,          // [B, S, M]
    const float* __restrict__ key_table,     // [KEY_SIZE, H]
    const float* __restrict__ value_table,   // [VALUE_SIZE, H]
    float*       __restrict__ out)           // [B, S, H]
{
    const int bs   = blockIdx.x;       // 0 .. B*S-1
    const int b    = bs / S;
    const int t    = threadIdx.x;      // 0 .. 255
    const int lane = t & 63;
    const int wave = t >> 6;           // 0 .. 3

    __shared__ float hs_s[H];          // hidden_state row (3 KB)
    __shared__ int   wseq_s[M];        // key indices for this batch
    __shared__ int   row_s[M];         // value row indices for this (b,s)
    __shared__ float p_s[M];           // exp(u)*mask, then normalized p
    __shared__ float red_s[4];         // per-wave partial sums

    // ---- stage inputs ----
    const float* hs_g   = hidden_state + (size_t)bs * H;
    const int*   lvm_g  = lvm          + (size_t)bs * M;
    const float* mask_g = mask         + (size_t)bs * M;

    for (int i = t; i < H; i += 256) hs_s[i] = hs_g[i];
    if (t < M) {
        wseq_s[t] = word_seq[b * M + t];
        row_s[t]  = lvm_g[t];
    }
    __syncthreads();

    // ---- phase A: u[m] = <hs, key_row>/sqrt(H); delta = exp(u)*clip(mask) ----
    const float inv_temper = 1.0f / sqrtf((float)H);
    const int m0 = wave * 32;
    for (int m = m0; m < m0 + 32; ++m) {
        const float* kr = key_table + (size_t)wseq_s[m] * H;
        float acc = 0.f;
        #pragma unroll
        for (int h = lane; h < H; h += 64) acc += hs_s[h] * kr[h];
        #pragma unroll
        for (int off = 32; off; off >>= 1) acc += __shfl_down(acc, off);
        if (lane == 0) {
            float mk = mask_g[m];
            mk = fminf(fmaxf(mk, 0.f), 1.f);
            p_s[m] = __expf(acc * inv_temper) * mk;
        }
    }
    __syncthreads();

    // ---- denominator + normalize ----
    float v = (t < M) ? p_s[t] : 0.f;
    #pragma unroll
    for (int off = 32; off; off >>= 1) v += __shfl_down(v, off);
    if (lane == 0) red_s[wave] = v;
    __syncthreads();
    const float denom = red_s[0] + red_s[1] + red_s[2] + red_s[3] + 1e-10f;
    const float inv_denom = 1.0f / denom;
    if (t < M) p_s[t] *= inv_denom;
    __syncthreads();

    // ---- phase B: o[h] = sum_m p[m] * value_table[row[m]][h] ----
    float acc0 = 0.f, acc1 = 0.f, acc2 = 0.f;
    for (int m = 0; m < M; ++m) {
        const float pm = p_s[m];
        const float* vr = value_table + (size_t)row_s[m] * H;
        acc0 += pm * vr[t];
        acc1 += pm * vr[t + 256];
        acc2 += pm * vr[t + 512];
    }
    float* og = out + (size_t)bs * H;
    og[t]       = acc0;
    og[t + 256] = acc1;
    og[t + 512] = acc2;
}

extern "C" void kernel_launch(void* const* d_in, const int* in_sizes, int n_in,
                              void* d_out, int out_size, void* d_ws, size_t ws_size,
                              hipStream_t stream) {
    const int*   word_seq    = (const int*)  d_in[0];
    const float* hidden      = (const float*)d_in[1];
    const int*   lvm         = (const int*)  d_in[2];
    const float* mask        = (const float*)d_in[3];
    const float* key_table   = (const float*)d_in[4];
    const float* value_table = (const float*)d_in[5];
    float* out = (float*)d_out;

    dim3 grid(B * S);
    dim3 block(256);
    kvmn_kernel<<<grid, block, 0, stream>>>(word_seq, hidden, lvm, mask,
                                            key_table, value_table, out);
}

// Round 2
// 276.746 us; speedup vs baseline: 1.3803x; 1.3803x over previous
//
#include <hip/hip_runtime.h>

// KVMN forward: o[b,s,:] = sum_m p[b,s,m] * value_table[lvm[b,s,m],:]
// p = masked-normalized exp(<hs[b,s], key_table[wseq[b,m]]>/sqrt(H))
//
// B=4 S=512 M=128 H=768. One block per (b,s), 192 threads (3 waves).
// Each thread owns one float4 chunk of H (192 chunks) in phase B.

constexpr int B = 4, S = 512, M = 128, H = 768;
constexpr int C4 = H / 4;   // 192 float4 chunks per row

__global__ __launch_bounds__(192) void kvmn_kernel(
    const int*   __restrict__ word_seq,      // [B, M]
    const float* __restrict__ hidden_state,  // [B, S, H]
    const int*   __restrict__ lvm,           // [B, S, M]
    const float* __restrict__ mask,          // [B, S, M]
    const float* __restrict__ key_table,     // [KEY_SIZE, H]
    const float* __restrict__ value_table,   // [VALUE_SIZE, H]
    float*       __restrict__ out)           // [B, S, H]
{
    const int bs   = blockIdx.x;       // 0 .. B*S-1
    const int b    = bs / S;
    const int t    = threadIdx.x;      // 0 .. 191
    const int lane = t & 63;
    const int wave = t >> 6;           // 0 .. 2

    __shared__ float4 hs4_s[C4];       // hidden_state row (3 KB)
    __shared__ int    wseq_s[M];       // key indices for this batch
    __shared__ int    row_s[M];        // value row indices for this (b,s)
    __shared__ float  p_s[M];          // exp(u)*mask, then normalized p
    __shared__ float  red_s[3];        // per-wave partial sums

    // ---- stage inputs ----
    const float4* hs_g4 = (const float4*)(hidden_state + (size_t)bs * H);
    hs4_s[t] = hs_g4[t];
    if (t < M) {
        wseq_s[t] = word_seq[b * M + t];
        row_s[t]  = lvm[(size_t)bs * M + t];
    }
    __syncthreads();

    // hidden row fragment for this lane, reused across all m
    const float4 h0 = hs4_s[lane];
    const float4 h1 = hs4_s[lane + 64];
    const float4 h2 = hs4_s[lane + 128];

    // ---- phase A: u[m] = <hs, key_row>/sqrt(H); p_s = exp(u)*clip(mask) ----
    const float inv_temper = rsqrtf((float)H);
    const float* mask_g = mask + (size_t)bs * M;
    for (int m = wave; m < M; m += 3) {
        const float4* kr = (const float4*)(key_table + (size_t)wseq_s[m] * H);
        const float4 k0 = kr[lane];
        const float4 k1 = kr[lane + 64];
        const float4 k2 = kr[lane + 128];
        float acc = h0.x*k0.x + h0.y*k0.y + h0.z*k0.z + h0.w*k0.w
                  + h1.x*k1.x + h1.y*k1.y + h1.z*k1.z + h1.w*k1.w
                  + h2.x*k2.x + h2.y*k2.y + h2.z*k2.z + h2.w*k2.w;
        #pragma unroll
        for (int off = 32; off; off >>= 1) acc += __shfl_down(acc, off);
        if (lane == 0) {
            float mk = mask_g[m];
            mk = fminf(fmaxf(mk, 0.f), 1.f);
            p_s[m] = __expf(acc * inv_temper) * mk;
        }
    }
    __syncthreads();

    // ---- denominator + normalize ----
    float v = (t < M) ? p_s[t] : 0.f;
    #pragma unroll
    for (int off = 32; off; off >>= 1) v += __shfl_down(v, off);
    if (lane == 0) red_s[wave] = v;
    __syncthreads();
    const float inv_denom = 1.0f / (red_s[0] + red_s[1] + red_s[2] + 1e-10f);
    if (t < M) p_s[t] *= inv_denom;
    __syncthreads();

    // ---- phase B: o4[c] = sum_m p[m] * vt4[row[m]*C4 + c], c = t ----
    const float4* vt4 = (const float4*)value_table;
    float4 a; a.x = a.y = a.z = a.w = 0.f;
    for (int m = 0; m < M; m += 4) {
        const float p0 = p_s[m + 0];
        const float p1 = p_s[m + 1];
        const float p2 = p_s[m + 2];
        const float p3 = p_s[m + 3];
        const float4 v0 = vt4[(size_t)row_s[m + 0] * C4 + t];
        const float4 v1 = vt4[(size_t)row_s[m + 1] * C4 + t];
        const float4 v2 = vt4[(size_t)row_s[m + 2] * C4 + t];
        const float4 v3 = vt4[(size_t)row_s[m + 3] * C4 + t];
        a.x += p0*v0.x + p1*v1.x + p2*v2.x + p3*v3.x;
        a.y += p0*v0.y + p1*v1.y + p2*v2.y + p3*v3.y;
        a.z += p0*v0.z + p1*v1.z + p2*v2.z + p3*v3.z;
        a.w += p0*v0.w + p1*v1.w + p2*v2.w + p3*v3.w;
    }
    ((float4*)(out + (size_t)bs * H))[t] = a;
}

extern "C" void kernel_launch(void* const* d_in, const int* in_sizes, int n_in,
                              void* d_out, int out_size, void* d_ws, size_t ws_size,
                              hipStream_t stream) {
    const int*   word_seq    = (const int*)  d_in[0];
    const float* hidden      = (const float*)d_in[1];
    const int*   lvm         = (const int*)  d_in[2];
    const float* mask        = (const float*)d_in[3];
    const float* key_table   = (const float*)d_in[4];
    const float* value_table = (const float*)d_in[5];
    float* out = (float*)d_out;

    dim3 grid(B * S);
    dim3 block(192);
    kvmn_kernel<<<grid, block, 0, stream>>>(word_seq, hidden, lvm, mask,
                                            key_table, value_table, out);
}

// Round 3
// 245.246 us; speedup vs baseline: 1.5575x; 1.1284x over previous
//
#include <hip/hip_runtime.h>

// KVMN forward: o[b,s,:] = (1/denom) * sum_m delta[m] * value_table[lvm[b,s,m],:]
//   delta[m] = exp(<hs[b,s], key_table[wseq[b,m]]>/sqrt(H)) * clip(mask,0,1)
//   denom    = sum_m delta[m] + 1e-10
//
// Normalization is linear -> defer it to the epilogue. Each wave owns a
// strided subset of m; per m it computes the key dot (butterfly reduce, all
// lanes get delta) and immediately FMAs delta * value-chunk into per-thread
// partials. No mid-loop barriers; key-load and value-load streams interleave.
//
// B=4 S=512 M=128 H=768. One block per (b,s), 192 threads (3 waves).

constexpr int B = 4, S = 512, M = 128, H = 768;
constexpr int C4 = H / 4;   // 192 float4 chunks per row

__global__ __launch_bounds__(192, 5) void kvmn_kernel(
    const int*   __restrict__ word_seq,      // [B, M]
    const float* __restrict__ hidden_state,  // [B, S, H]
    const int*   __restrict__ lvm,           // [B, S, M]
    const float* __restrict__ mask,          // [B, S, M]
    const float* __restrict__ key_table,     // [KEY_SIZE, H]
    const float* __restrict__ value_table,   // [VALUE_SIZE, H]
    float*       __restrict__ out)           // [B, S, H]
{
    const int bs   = blockIdx.x;       // 0 .. B*S-1
    const int b    = bs / S;
    const int t    = threadIdx.x;      // 0 .. 191
    const int lane = t & 63;
    const int wave = t >> 6;           // 0 .. 2

    __shared__ float4 hs4_s[C4];       // hidden_state row (3 KB)
    __shared__ int    wseq_s[M];
    __shared__ int    row_s[M];
    __shared__ float  mask_s[M];
    __shared__ float4 obuf[3][C4];     // per-wave O partials (9 KB)
    __shared__ float  dsum_s[3];

    // ---- stage inputs ----
    const float4* hs_g4 = (const float4*)(hidden_state + (size_t)bs * H);
    hs4_s[t] = hs_g4[t];
    if (t < M) {
        wseq_s[t] = word_seq[b * M + t];
        row_s[t]  = lvm[(size_t)bs * M + t];
        float mk  = mask[(size_t)bs * M + t];
        mask_s[t] = fminf(fmaxf(mk, 0.f), 1.f);
    }
    __syncthreads();

    const float4 h0 = hs4_s[lane];
    const float4 h1 = hs4_s[lane + 64];
    const float4 h2 = hs4_s[lane + 128];

    const float inv_temper = rsqrtf((float)H);
    const float4* kt4 = (const float4*)key_table;
    const float4* vt4 = (const float4*)value_table;

    float4 a0 = {0.f, 0.f, 0.f, 0.f};
    float4 a1 = {0.f, 0.f, 0.f, 0.f};
    float4 a2 = {0.f, 0.f, 0.f, 0.f};
    float  dsum = 0.f;

    #pragma unroll 2
    for (int m = wave; m < M; m += 3) {
        const float4* kr = kt4 + (size_t)wseq_s[m] * C4;
        const float4* vr = vt4 + (size_t)row_s[m]  * C4;
        const float4 k0 = kr[lane];
        const float4 k1 = kr[lane + 64];
        const float4 k2 = kr[lane + 128];
        const float4 v0 = vr[lane];
        const float4 v1 = vr[lane + 64];
        const float4 v2 = vr[lane + 128];

        float dot = h0.x*k0.x + h0.y*k0.y + h0.z*k0.z + h0.w*k0.w
                  + h1.x*k1.x + h1.y*k1.y + h1.z*k1.z + h1.w*k1.w
                  + h2.x*k2.x + h2.y*k2.y + h2.z*k2.z + h2.w*k2.w;
        #pragma unroll
        for (int off = 1; off < 64; off <<= 1) dot += __shfl_xor(dot, off);

        const float delta = __expf(dot * inv_temper) * mask_s[m];
        dsum += delta;

        a0.x += delta*v0.x; a0.y += delta*v0.y; a0.z += delta*v0.z; a0.w += delta*v0.w;
        a1.x += delta*v1.x; a1.y += delta*v1.y; a1.z += delta*v1.z; a1.w += delta*v1.w;
        a2.x += delta*v2.x; a2.y += delta*v2.y; a2.z += delta*v2.z; a2.w += delta*v2.w;
    }

    // ---- cross-wave reduction ----
    obuf[wave][lane]       = a0;
    obuf[wave][lane + 64]  = a1;
    obuf[wave][lane + 128] = a2;
    if (lane == 0) dsum_s[wave] = dsum;   // all lanes hold the same dsum
    __syncthreads();

    const float inv_d = 1.0f / (dsum_s[0] + dsum_s[1] + dsum_s[2] + 1e-10f);
    const float4 r0 = obuf[0][t];
    const float4 r1 = obuf[1][t];
    const float4 r2 = obuf[2][t];
    float4 r;
    r.x = (r0.x + r1.x + r2.x) * inv_d;
    r.y = (r0.y + r1.y + r2.y) * inv_d;
    r.z = (r0.z + r1.z + r2.z) * inv_d;
    r.w = (r0.w + r1.w + r2.w) * inv_d;
    ((float4*)(out + (size_t)bs * H))[t] = r;
}

extern "C" void kernel_launch(void* const* d_in, const int* in_sizes, int n_in,
                              void* d_out, int out_size, void* d_ws, size_t ws_size,
                              hipStream_t stream) {
    const int*   word_seq    = (const int*)  d_in[0];
    const float* hidden      = (const float*)d_in[1];
    const int*   lvm         = (const int*)  d_in[2];
    const float* mask        = (const float*)d_in[3];
    const float* key_table   = (const float*)d_in[4];
    const float* value_table = (const float*)d_in[5];
    float* out = (float*)d_out;

    dim3 grid(B * S);
    dim3 block(192);
    kvmn_kernel<<<grid, block, 0, stream>>>(word_seq, hidden, lvm, mask,
                                            key_table, value_table, out);
}

// Round 4
// 212.228 us; speedup vs baseline: 1.7999x; 1.1556x over previous
//
#include <hip/hip_runtime.h>
#include <hip/hip_bf16.h>

// KVMN forward: o[b,s,:] = (1/denom) * sum_m delta[m] * value_table[lvm[b,s,m],:]
//   delta[m] = exp(<hs[b,s], key_table[wseq[b,m]]>/sqrt(H)) * clip(mask,0,1)
//
// R4: tables converted to bf16 in d_ws by a prologue kernel (halves gather
// bytes; keys also compacted to the B*M used rows). Fused main kernel as R3
// but bf16 loads + deep unroll, no min-occupancy clamp on VGPRs.

constexpr int B = 4, S = 512, M = 128, H = 768;
constexpr int C4 = H / 4;                 // 192 float4 chunks per row
constexpr int KEY_SIZE = 30000, VALUE_SIZE = 10000;

constexpr int    VT_N      = VALUE_SIZE * H;          // 7,680,000 elems
constexpr int    KA_N      = B * M * H;               // 393,216 elems
constexpr size_t VT_BYTES  = (size_t)VT_N * 2;        // 15,360,000
constexpr size_t WS_NEEDED = VT_BYTES + (size_t)KA_N * 2;
constexpr int    VT_V4     = VT_N / 4;                // ushort4 items
constexpr int    KA_V4     = KA_N / 4;
constexpr int    CONV_TOTAL = VT_V4 + KA_V4;

__device__ inline unsigned short f2bf(float f) {
    __hip_bfloat16 h = __float2bfloat16(f);           // RNE
    return *reinterpret_cast<unsigned short*>(&h);
}
__device__ inline float bf2f(unsigned short u) {
    return __uint_as_float((unsigned)u << 16);
}
__device__ inline float4 bf4_to_f4(ushort4 u) {
    float4 f;
    f.x = bf2f(u.x); f.y = bf2f(u.y); f.z = bf2f(u.z); f.w = bf2f(u.w);
    return f;
}

// ---- prologue: value_table -> bf16; gather+convert used key rows ----
__global__ __launch_bounds__(256) void convert_kernel(
    const float* __restrict__ vt, const float* __restrict__ kt,
    const int* __restrict__ wseq,
    unsigned short* __restrict__ vt_bf, unsigned short* __restrict__ ka_bf)
{
    int i = blockIdx.x * 256 + threadIdx.x;
    if (i < VT_V4) {
        float4 f = ((const float4*)vt)[i];
        ushort4 u; u.x = f2bf(f.x); u.y = f2bf(f.y); u.z = f2bf(f.z); u.w = f2bf(f.w);
        ((ushort4*)vt_bf)[i] = u;
    } else if (i < CONV_TOTAL) {
        int j   = i - VT_V4;
        int c   = j % (H / 4);
        int row = j / (H / 4);                        // b*M + m
        int src = wseq[row];
        float4 f = ((const float4*)(kt + (size_t)src * H))[c];
        ushort4 u; u.x = f2bf(f.x); u.y = f2bf(f.y); u.z = f2bf(f.z); u.w = f2bf(f.w);
        ((ushort4*)ka_bf)[j] = u;
    }
}

// ---- fused main kernel (bf16 tables) ----
__global__ __launch_bounds__(192) void kvmn_bf16_kernel(
    const float* __restrict__ hidden_state,   // [B,S,H] fp32
    const int*   __restrict__ lvm,            // [B,S,M]
    const float* __restrict__ mask,           // [B,S,M]
    const unsigned short* __restrict__ ka_bf, // [B,M,H] bf16 (compacted keys)
    const unsigned short* __restrict__ vt_bf, // [VALUE_SIZE,H] bf16
    float*       __restrict__ out)            // [B,S,H]
{
    const int bs   = blockIdx.x;
    const int b    = bs / S;
    const int t    = threadIdx.x;
    const int lane = t & 63;
    const int wave = t >> 6;

    __shared__ float4 hs4_s[C4];
    __shared__ int    row_s[M];
    __shared__ float  mask_s[M];
    __shared__ float4 obuf[3][C4];
    __shared__ float  dsum_s[3];

    const float4* hs_g4 = (const float4*)(hidden_state + (size_t)bs * H);
    hs4_s[t] = hs_g4[t];
    if (t < M) {
        row_s[t]  = lvm[(size_t)bs * M + t];
        float mk  = mask[(size_t)bs * M + t];
        mask_s[t] = fminf(fmaxf(mk, 0.f), 1.f);
    }
    __syncthreads();

    const float4 h0 = hs4_s[lane];
    const float4 h1 = hs4_s[lane + 64];
    const float4 h2 = hs4_s[lane + 128];

    const float inv_temper = rsqrtf((float)H);

    float4 a0 = {0.f, 0.f, 0.f, 0.f};
    float4 a1 = {0.f, 0.f, 0.f, 0.f};
    float4 a2 = {0.f, 0.f, 0.f, 0.f};
    float  dsum = 0.f;

    #pragma unroll 4
    for (int m = wave; m < M; m += 3) {
        const ushort4* kr = (const ushort4*)(ka_bf + ((size_t)(b * M + m)) * H);
        const ushort4* vr = (const ushort4*)(vt_bf + (size_t)row_s[m] * H);
        const ushort4 ku0 = kr[lane];
        const ushort4 ku1 = kr[lane + 64];
        const ushort4 ku2 = kr[lane + 128];
        const ushort4 vu0 = vr[lane];
        const ushort4 vu1 = vr[lane + 64];
        const ushort4 vu2 = vr[lane + 128];

        const float4 k0 = bf4_to_f4(ku0);
        const float4 k1 = bf4_to_f4(ku1);
        const float4 k2 = bf4_to_f4(ku2);

        float dot = h0.x*k0.x + h0.y*k0.y + h0.z*k0.z + h0.w*k0.w
                  + h1.x*k1.x + h1.y*k1.y + h1.z*k1.z + h1.w*k1.w
                  + h2.x*k2.x + h2.y*k2.y + h2.z*k2.z + h2.w*k2.w;
        #pragma unroll
        for (int off = 1; off < 64; off <<= 1) dot += __shfl_xor(dot, off);

        const float delta = __expf(dot * inv_temper) * mask_s[m];
        dsum += delta;

        const float4 v0 = bf4_to_f4(vu0);
        const float4 v1 = bf4_to_f4(vu1);
        const float4 v2 = bf4_to_f4(vu2);
        a0.x += delta*v0.x; a0.y += delta*v0.y; a0.z += delta*v0.z; a0.w += delta*v0.w;
        a1.x += delta*v1.x; a1.y += delta*v1.y; a1.z += delta*v1.z; a1.w += delta*v1.w;
        a2.x += delta*v2.x; a2.y += delta*v2.y; a2.z += delta*v2.z; a2.w += delta*v2.w;
    }

    obuf[wave][lane]       = a0;
    obuf[wave][lane + 64]  = a1;
    obuf[wave][lane + 128] = a2;
    if (lane == 0) dsum_s[wave] = dsum;
    __syncthreads();

    const float inv_d = 1.0f / (dsum_s[0] + dsum_s[1] + dsum_s[2] + 1e-10f);
    const float4 r0 = obuf[0][t];
    const float4 r1 = obuf[1][t];
    const float4 r2 = obuf[2][t];
    float4 r;
    r.x = (r0.x + r1.x + r2.x) * inv_d;
    r.y = (r0.y + r1.y + r2.y) * inv_d;
    r.z = (r0.z + r1.z + r2.z) * inv_d;
    r.w = (r0.w + r1.w + r2.w) * inv_d;
    ((float4*)(out + (size_t)bs * H))[t] = r;
}

// ---- fallback: R3 fp32 fused kernel (used only if ws too small) ----
__global__ __launch_bounds__(192) void kvmn_fp32_kernel(
    const int*   __restrict__ word_seq,
    const float* __restrict__ hidden_state,
    const int*   __restrict__ lvm,
    const float* __restrict__ mask,
    const float* __restrict__ key_table,
    const float* __restrict__ value_table,
    float*       __restrict__ out)
{
    const int bs   = blockIdx.x;
    const int b    = bs / S;
    const int t    = threadIdx.x;
    const int lane = t & 63;
    const int wave = t >> 6;

    __shared__ float4 hs4_s[C4];
    __shared__ int    wseq_s[M];
    __shared__ int    row_s[M];
    __shared__ float  mask_s[M];
    __shared__ float4 obuf[3][C4];
    __shared__ float  dsum_s[3];

    const float4* hs_g4 = (const float4*)(hidden_state + (size_t)bs * H);
    hs4_s[t] = hs_g4[t];
    if (t < M) {
        wseq_s[t] = word_seq[b * M + t];
        row_s[t]  = lvm[(size_t)bs * M + t];
        float mk  = mask[(size_t)bs * M + t];
        mask_s[t] = fminf(fmaxf(mk, 0.f), 1.f);
    }
    __syncthreads();

    const float4 h0 = hs4_s[lane];
    const float4 h1 = hs4_s[lane + 64];
    const float4 h2 = hs4_s[lane + 128];
    const float inv_temper = rsqrtf((float)H);
    const float4* kt4 = (const float4*)key_table;
    const float4* vt4 = (const float4*)value_table;

    float4 a0 = {0.f,0.f,0.f,0.f}, a1 = {0.f,0.f,0.f,0.f}, a2 = {0.f,0.f,0.f,0.f};
    float dsum = 0.f;

    #pragma unroll 2
    for (int m = wave; m < M; m += 3) {
        const float4* kr = kt4 + (size_t)wseq_s[m] * C4;
        const float4* vr = vt4 + (size_t)row_s[m]  * C4;
        const float4 k0 = kr[lane], k1 = kr[lane+64], k2 = kr[lane+128];
        const float4 v0 = vr[lane], v1 = vr[lane+64], v2 = vr[lane+128];
        float dot = h0.x*k0.x + h0.y*k0.y + h0.z*k0.z + h0.w*k0.w
                  + h1.x*k1.x + h1.y*k1.y + h1.z*k1.z + h1.w*k1.w
                  + h2.x*k2.x + h2.y*k2.y + h2.z*k2.z + h2.w*k2.w;
        #pragma unroll
        for (int off = 1; off < 64; off <<= 1) dot += __shfl_xor(dot, off);
        const float delta = __expf(dot * inv_temper) * mask_s[m];
        dsum += delta;
        a0.x += delta*v0.x; a0.y += delta*v0.y; a0.z += delta*v0.z; a0.w += delta*v0.w;
        a1.x += delta*v1.x; a1.y += delta*v1.y; a1.z += delta*v1.z; a1.w += delta*v1.w;
        a2.x += delta*v2.x; a2.y += delta*v2.y; a2.z += delta*v2.z; a2.w += delta*v2.w;
    }
    obuf[wave][lane] = a0; obuf[wave][lane+64] = a1; obuf[wave][lane+128] = a2;
    if (lane == 0) dsum_s[wave] = dsum;
    __syncthreads();
    const float inv_d = 1.0f / (dsum_s[0] + dsum_s[1] + dsum_s[2] + 1e-10f);
    const float4 r0 = obuf[0][t], r1 = obuf[1][t], r2 = obuf[2][t];
    float4 r;
    r.x = (r0.x+r1.x+r2.x)*inv_d; r.y = (r0.y+r1.y+r2.y)*inv_d;
    r.z = (r0.z+r1.z+r2.z)*inv_d; r.w = (r0.w+r1.w+r2.w)*inv_d;
    ((float4*)(out + (size_t)bs * H))[t] = r;
}

extern "C" void kernel_launch(void* const* d_in, const int* in_sizes, int n_in,
                              void* d_out, int out_size, void* d_ws, size_t ws_size,
                              hipStream_t stream) {
    const int*   word_seq    = (const int*)  d_in[0];
    const float* hidden      = (const float*)d_in[1];
    const int*   lvm         = (const int*)  d_in[2];
    const float* mask        = (const float*)d_in[3];
    const float* key_table   = (const float*)d_in[4];
    const float* value_table = (const float*)d_in[5];
    float* out = (float*)d_out;

    if (ws_size >= WS_NEEDED) {
        unsigned short* vt_bf = (unsigned short*)d_ws;
        unsigned short* ka_bf = (unsigned short*)((char*)d_ws + VT_BYTES);
        convert_kernel<<<(CONV_TOTAL + 255) / 256, 256, 0, stream>>>(
            value_table, key_table, word_seq, vt_bf, ka_bf);
        kvmn_bf16_kernel<<<B * S, 192, 0, stream>>>(
            hidden, lvm, mask, ka_bf, vt_bf, out);
    } else {
        kvmn_fp32_kernel<<<B * S, 192, 0, stream>>>(
            word_seq, hidden, lvm, mask, key_table, value_table, out);
    }
}

// Round 5
// 206.290 us; speedup vs baseline: 1.8517x; 1.0288x over previous
//
#include <hip/hip_runtime.h>
#include <hip/hip_bf16.h>

// KVMN forward, 3-kernel pipeline:
//  1) convert: value_table -> bf16, gather+convert used key rows (B*M), hidden -> bf16
//  2) phaseA : u[b,s,m] = <hs[b,s], ka[b,m]> via MFMA bf16 GEMM (u raw, no scale)
//  3) gather : delta = exp(u/sqrt(H))*clip(mask); o = sum_m delta*vt[row]; normalize
//
// B=4 S=512 M=128 H=768.

constexpr int B = 4, S = 512, M = 128, H = 768;
constexpr int C4 = H / 4;                 // 192 float4 / ushort4 chunks per row
constexpr int KEY_SIZE = 30000, VALUE_SIZE = 10000;

constexpr int VT_N = VALUE_SIZE * H;      // 7,680,000
constexpr int KA_N = B * M * H;           //   393,216
constexpr int HS_N = B * S * H;           // 1,572,864
constexpr int U_N  = B * S * M;           //   262,144

constexpr size_t VT_BYTES = (size_t)VT_N * 2;
constexpr size_t KA_BYTES = (size_t)KA_N * 2;
constexpr size_t HS_BYTES = (size_t)HS_N * 2;
constexpr size_t U_BYTES  = (size_t)U_N  * 4;
constexpr size_t WS_NEEDED = VT_BYTES + KA_BYTES + HS_BYTES + U_BYTES;  // ~20.3 MB

constexpr int VT_V4 = VT_N / 4, KA_V4 = KA_N / 4, HS_V4 = HS_N / 4;
constexpr int CONV_TOTAL = VT_V4 + KA_V4 + HS_V4;

typedef short  bf16x8  __attribute__((ext_vector_type(8)));
typedef float  floatx4 __attribute__((ext_vector_type(4)));

__device__ inline unsigned short f2bf(float f) {
    __hip_bfloat16 h = __float2bfloat16(f);           // RNE
    return *reinterpret_cast<unsigned short*>(&h);
}
__device__ inline float bf2f(unsigned short u) {
    return __uint_as_float((unsigned)u << 16);
}
__device__ inline float4 bf4_to_f4(ushort4 u) {
    float4 f;
    f.x = bf2f(u.x); f.y = bf2f(u.y); f.z = bf2f(u.z); f.w = bf2f(u.w);
    return f;
}
__device__ inline ushort4 f4_to_bf4(float4 f) {
    ushort4 u; u.x = f2bf(f.x); u.y = f2bf(f.y); u.z = f2bf(f.z); u.w = f2bf(f.w);
    return u;
}

// ---- kernel 1: convert tables + hidden to bf16 (keys compacted via word_seq) ----
__global__ __launch_bounds__(256) void convert_kernel(
    const float* __restrict__ vt, const float* __restrict__ kt,
    const float* __restrict__ hs, const int* __restrict__ wseq,
    unsigned short* __restrict__ vt_bf, unsigned short* __restrict__ ka_bf,
    unsigned short* __restrict__ hs_bf)
{
    int i = blockIdx.x * 256 + threadIdx.x;
    if (i < VT_V4) {
        ((ushort4*)vt_bf)[i] = f4_to_bf4(((const float4*)vt)[i]);
    } else if (i < VT_V4 + KA_V4) {
        int j   = i - VT_V4;
        int c   = j % (H / 4);
        int row = j / (H / 4);                        // b*M + m
        int src = wseq[row];
        float4 f = ((const float4*)(kt + (size_t)src * H))[c];
        ((ushort4*)ka_bf)[j] = f4_to_bf4(f);
    } else if (i < CONV_TOTAL) {
        int j = i - VT_V4 - KA_V4;
        ((ushort4*)hs_bf)[j] = f4_to_bf4(((const float4*)hs)[j]);
    }
}

// ---- kernel 2: u = hs . ka^T  (per b), MFMA 16x16x32 bf16 ----
// 1024 tiles of 16x16 (4 b * 32 s-tiles * 8 m-tiles); one wave per tile.
__global__ __launch_bounds__(256) void phaseA_kernel(
    const unsigned short* __restrict__ hs_bf,   // [B,S,H]
    const unsigned short* __restrict__ ka_bf,   // [B,M,H]
    float* __restrict__ u_ws)                   // [B,S,M]
{
    const int lane = threadIdx.x & 63;
    const int wave = threadIdx.x >> 6;
    const int tile = blockIdx.x * 4 + wave;     // 0..1023
    const int b    = tile >> 8;                 // 256 tiles per b
    const int r    = tile & 255;
    const int s0   = (r >> 3) << 4;             // s-tile * 16
    const int m0   = (r & 7) << 4;              // m-tile * 16
    const int l15  = lane & 15;
    const int quad = lane >> 4;

    const unsigned short* arow = hs_bf + (size_t)(b * S + s0 + l15) * H + quad * 8;
    const unsigned short* brow = ka_bf + (size_t)(b * M + m0 + l15) * H + quad * 8;

    floatx4 acc = {0.f, 0.f, 0.f, 0.f};
    #pragma unroll 4
    for (int k = 0; k < H; k += 32) {
        bf16x8 af = *(const bf16x8*)(arow + k);
        bf16x8 bf = *(const bf16x8*)(brow + k);
        acc = __builtin_amdgcn_mfma_f32_16x16x32_bf16(af, bf, acc, 0, 0, 0);
    }
    // C/D: col(=m) = lane&15, row(=s) = quad*4 + reg
    float* up = u_ws + (size_t)(b * S + s0 + quad * 4) * M + m0 + l15;
    up[0 * M] = acc[0];
    up[1 * M] = acc[1];
    up[2 * M] = acc[2];
    up[3 * M] = acc[3];
}

// ---- kernel 3: gather + weighted sum + normalize. 384 thr (6 waves) per (b,s) ----
constexpr int GW = 6;
__global__ __launch_bounds__(384) void gather_kernel(
    const float* __restrict__ u_ws,             // [B,S,M]
    const int*   __restrict__ lvm,              // [B,S,M]
    const float* __restrict__ mask,             // [B,S,M]
    const unsigned short* __restrict__ vt_bf,   // [VALUE_SIZE,H]
    float*       __restrict__ out)              // [B,S,H]
{
    const int bs   = blockIdx.x;
    const int t    = threadIdx.x;
    const int lane = t & 63;
    const int wave = t >> 6;

    __shared__ float  delta_s[M];
    __shared__ int    row_s[M];
    __shared__ float4 obuf[GW][C4];   // 18 KB
    __shared__ float  dsum_s[GW];

    const float inv_temper = rsqrtf((float)H);
    if (t < M) {
        float u  = u_ws[(size_t)bs * M + t];
        float mk = mask[(size_t)bs * M + t];
        mk = fminf(fmaxf(mk, 0.f), 1.f);
        delta_s[t] = __expf(u * inv_temper) * mk;
        row_s[t]   = lvm[(size_t)bs * M + t];
    }
    __syncthreads();

    float4 a0 = {0.f,0.f,0.f,0.f}, a1 = {0.f,0.f,0.f,0.f}, a2 = {0.f,0.f,0.f,0.f};
    float dsum = 0.f;

    #pragma unroll 4
    for (int m = wave; m < M; m += GW) {
        const float pm = delta_s[m];
        const ushort4* vr = (const ushort4*)(vt_bf + (size_t)row_s[m] * H);
        const ushort4 vu0 = vr[lane];
        const ushort4 vu1 = vr[lane + 64];
        const ushort4 vu2 = vr[lane + 128];
        dsum += pm;
        const float4 v0 = bf4_to_f4(vu0);
        const float4 v1 = bf4_to_f4(vu1);
        const float4 v2 = bf4_to_f4(vu2);
        a0.x += pm*v0.x; a0.y += pm*v0.y; a0.z += pm*v0.z; a0.w += pm*v0.w;
        a1.x += pm*v1.x; a1.y += pm*v1.y; a1.z += pm*v1.z; a1.w += pm*v1.w;
        a2.x += pm*v2.x; a2.y += pm*v2.y; a2.z += pm*v2.z; a2.w += pm*v2.w;
    }

    obuf[wave][lane]       = a0;
    obuf[wave][lane + 64]  = a1;
    obuf[wave][lane + 128] = a2;
    if (lane == 0) dsum_s[wave] = dsum;
    __syncthreads();

    if (t < C4) {
        float d = 1e-10f;
        #pragma unroll
        for (int w = 0; w < GW; ++w) d += dsum_s[w];
        const float inv_d = 1.0f / d;
        float4 r = {0.f, 0.f, 0.f, 0.f};
        #pragma unroll
        for (int w = 0; w < GW; ++w) {
            const float4 o = obuf[w][t];
            r.x += o.x; r.y += o.y; r.z += o.z; r.w += o.w;
        }
        r.x *= inv_d; r.y *= inv_d; r.z *= inv_d; r.w *= inv_d;
        ((float4*)(out + (size_t)bs * H))[t] = r;
    }
}

// ---- fallback: fused fp32 (only if ws too small) ----
__global__ __launch_bounds__(192) void kvmn_fp32_kernel(
    const int*   __restrict__ word_seq,
    const float* __restrict__ hidden_state,
    const int*   __restrict__ lvm,
    const float* __restrict__ mask,
    const float* __restrict__ key_table,
    const float* __restrict__ value_table,
    float*       __restrict__ out)
{
    const int bs   = blockIdx.x;
    const int b    = bs / S;
    const int t    = threadIdx.x;
    const int lane = t & 63;
    const int wave = t >> 6;

    __shared__ float4 hs4_s[C4];
    __shared__ int    wseq_s[M];
    __shared__ int    row_s[M];
    __shared__ float  mask_s[M];
    __shared__ float4 obuf[3][C4];
    __shared__ float  dsum_s[3];

    const float4* hs_g4 = (const float4*)(hidden_state + (size_t)bs * H);
    hs4_s[t] = hs_g4[t];
    if (t < M) {
        wseq_s[t] = word_seq[b * M + t];
        row_s[t]  = lvm[(size_t)bs * M + t];
        float mk  = mask[(size_t)bs * M + t];
        mask_s[t] = fminf(fmaxf(mk, 0.f), 1.f);
    }
    __syncthreads();

    const float4 h0 = hs4_s[lane];
    const float4 h1 = hs4_s[lane + 64];
    const float4 h2 = hs4_s[lane + 128];
    const float inv_temper = rsqrtf((float)H);
    const float4* kt4 = (const float4*)key_table;
    const float4* vt4 = (const float4*)value_table;

    float4 a0 = {0.f,0.f,0.f,0.f}, a1 = {0.f,0.f,0.f,0.f}, a2 = {0.f,0.f,0.f,0.f};
    float dsum = 0.f;

    #pragma unroll 2
    for (int m = wave; m < M; m += 3) {
        const float4* kr = kt4 + (size_t)wseq_s[m] * C4;
        const float4* vr = vt4 + (size_t)row_s[m]  * C4;
        const float4 k0 = kr[lane], k1 = kr[lane+64], k2 = kr[lane+128];
        const float4 v0 = vr[lane], v1 = vr[lane+64], v2 = vr[lane+128];
        float dot = h0.x*k0.x + h0.y*k0.y + h0.z*k0.z + h0.w*k0.w
                  + h1.x*k1.x + h1.y*k1.y + h1.z*k1.z + h1.w*k1.w
                  + h2.x*k2.x + h2.y*k2.y + h2.z*k2.z + h2.w*k2.w;
        #pragma unroll
        for (int off = 1; off < 64; off <<= 1) dot += __shfl_xor(dot, off);
        const float delta = __expf(dot * inv_temper) * mask_s[m];
        dsum += delta;
        a0.x += delta*v0.x; a0.y += delta*v0.y; a0.z += delta*v0.z; a0.w += delta*v0.w;
        a1.x += delta*v1.x; a1.y += delta*v1.y; a1.z += delta*v1.z; a1.w += delta*v1.w;
        a2.x += delta*v2.x; a2.y += delta*v2.y; a2.z += delta*v2.z; a2.w += delta*v2.w;
    }
    obuf[wave][lane] = a0; obuf[wave][lane+64] = a1; obuf[wave][lane+128] = a2;
    if (lane == 0) dsum_s[wave] = dsum;
    __syncthreads();
    const float inv_d = 1.0f / (dsum_s[0] + dsum_s[1] + dsum_s[2] + 1e-10f);
    const float4 r0 = obuf[0][t], r1 = obuf[1][t], r2 = obuf[2][t];
    float4 r;
    r.x = (r0.x+r1.x+r2.x)*inv_d; r.y = (r0.y+r1.y+r2.y)*inv_d;
    r.z = (r0.z+r1.z+r2.z)*inv_d; r.w = (r0.w+r1.w+r2.w)*inv_d;
    ((float4*)(out + (size_t)bs * H))[t] = r;
}

extern "C" void kernel_launch(void* const* d_in, const int* in_sizes, int n_in,
                              void* d_out, int out_size, void* d_ws, size_t ws_size,
                              hipStream_t stream) {
    const int*   word_seq    = (const int*)  d_in[0];
    const float* hidden      = (const float*)d_in[1];
    const int*   lvm         = (const int*)  d_in[2];
    const float* mask        = (const float*)d_in[3];
    const float* key_table   = (const float*)d_in[4];
    const float* value_table = (const float*)d_in[5];
    float* out = (float*)d_out;

    if (ws_size >= WS_NEEDED) {
        unsigned short* vt_bf = (unsigned short*)d_ws;
        unsigned short* ka_bf = (unsigned short*)((char*)d_ws + VT_BYTES);
        unsigned short* hs_bf = (unsigned short*)((char*)d_ws + VT_BYTES + KA_BYTES);
        float*          u_ws  = (float*)((char*)d_ws + VT_BYTES + KA_BYTES + HS_BYTES);

        convert_kernel<<<(CONV_TOTAL + 255) / 256, 256, 0, stream>>>(
            value_table, key_table, hidden, word_seq, vt_bf, ka_bf, hs_bf);
        phaseA_kernel<<<(B * S / 16) * (M / 16) / 4, 256, 0, stream>>>(
            hs_bf, ka_bf, u_ws);
        gather_kernel<<<B * S, 64 * GW, 0, stream>>>(
            u_ws, lvm, mask, vt_bf, out);
    } else {
        kvmn_fp32_kernel<<<B * S, 192, 0, stream>>>(
            word_seq, hidden, lvm, mask, key_table, value_table, out);
    }
}

// Round 6
// 203.890 us; speedup vs baseline: 1.8735x; 1.0118x over previous
//
#include <hip/hip_runtime.h>
#include <hip/hip_bf16.h>

// KVMN forward, 3-kernel pipeline:
//  1) convert: value_table -> bf16, gather+convert used key rows (B*M), hidden -> bf16
//  2) phaseA : u[b,s,m] = <hs[b,s], ka[b,m]> via MFMA bf16 GEMM (u raw, no scale)
//  3) gather : delta = exp(u/sqrt(H))*clip(mask); o = sum_m delta*vt[row]; normalize
//
// B=4 S=512 M=128 H=768.

constexpr int B = 4, S = 512, M = 128, H = 768;
constexpr int C4 = H / 4;                 // 192 float4 / ushort4 chunks per row
constexpr int KEY_SIZE = 30000, VALUE_SIZE = 10000;

constexpr int VT_N = VALUE_SIZE * H;      // 7,680,000
constexpr int KA_N = B * M * H;           //   393,216
constexpr int HS_N = B * S * H;           // 1,572,864
constexpr int U_N  = B * S * M;           //   262,144

constexpr size_t VT_BYTES = (size_t)VT_N * 2;
constexpr size_t KA_BYTES = (size_t)KA_N * 2;
constexpr size_t HS_BYTES = (size_t)HS_N * 2;
constexpr size_t U_BYTES  = (size_t)U_N  * 4;
constexpr size_t WS_NEEDED = VT_BYTES + KA_BYTES + HS_BYTES + U_BYTES;  // ~20.3 MB

constexpr int VT_V4 = VT_N / 4, KA_V4 = KA_N / 4, HS_V4 = HS_N / 4;
constexpr int CONV_TOTAL = VT_V4 + KA_V4 + HS_V4;

typedef short          bf16x8  __attribute__((ext_vector_type(8)));
typedef float          floatx4 __attribute__((ext_vector_type(4)));
typedef unsigned short ushort8v __attribute__((ext_vector_type(8)));

__device__ inline unsigned short f2bf(float f) {
    __hip_bfloat16 h = __float2bfloat16(f);           // RNE
    return *reinterpret_cast<unsigned short*>(&h);
}
__device__ inline float bf2f(unsigned short u) {
    return __uint_as_float((unsigned)u << 16);
}
__device__ inline ushort4 f4_to_bf4(float4 f) {
    ushort4 u; u.x = f2bf(f.x); u.y = f2bf(f.y); u.z = f2bf(f.z); u.w = f2bf(f.w);
    return u;
}

// ---- kernel 1: convert tables + hidden to bf16 (keys compacted via word_seq) ----
__global__ __launch_bounds__(256) void convert_kernel(
    const float* __restrict__ vt, const float* __restrict__ kt,
    const float* __restrict__ hs, const int* __restrict__ wseq,
    unsigned short* __restrict__ vt_bf, unsigned short* __restrict__ ka_bf,
    unsigned short* __restrict__ hs_bf)
{
    int i = blockIdx.x * 256 + threadIdx.x;
    if (i < VT_V4) {
        ((ushort4*)vt_bf)[i] = f4_to_bf4(((const float4*)vt)[i]);
    } else if (i < VT_V4 + KA_V4) {
        int j   = i - VT_V4;
        int c   = j % (H / 4);
        int row = j / (H / 4);                        // b*M + m
        int src = wseq[row];
        float4 f = ((const float4*)(kt + (size_t)src * H))[c];
        ((ushort4*)ka_bf)[j] = f4_to_bf4(f);
    } else if (i < CONV_TOTAL) {
        int j = i - VT_V4 - KA_V4;
        ((ushort4*)hs_bf)[j] = f4_to_bf4(((const float4*)hs)[j]);
    }
}

// ---- kernel 2: u = hs . ka^T  (per b), MFMA 16x16x32 bf16 ----
// 1024 tiles of 16x16 (4 b * 32 s-tiles * 8 m-tiles); one wave per tile.
__global__ __launch_bounds__(256) void phaseA_kernel(
    const unsigned short* __restrict__ hs_bf,   // [B,S,H]
    const unsigned short* __restrict__ ka_bf,   // [B,M,H]
    float* __restrict__ u_ws)                   // [B,S,M]
{
    const int lane = threadIdx.x & 63;
    const int wave = threadIdx.x >> 6;
    const int tile = blockIdx.x * 4 + wave;     // 0..1023
    const int b    = tile >> 8;                 // 256 tiles per b
    const int r    = tile & 255;
    const int s0   = (r >> 3) << 4;             // s-tile * 16
    const int m0   = (r & 7) << 4;              // m-tile * 16
    const int l15  = lane & 15;
    const int quad = lane >> 4;

    const unsigned short* arow = hs_bf + (size_t)(b * S + s0 + l15) * H + quad * 8;
    const unsigned short* brow = ka_bf + (size_t)(b * M + m0 + l15) * H + quad * 8;

    floatx4 acc = {0.f, 0.f, 0.f, 0.f};
    #pragma unroll 4
    for (int k = 0; k < H; k += 32) {
        bf16x8 af = *(const bf16x8*)(arow + k);
        bf16x8 bf = *(const bf16x8*)(brow + k);
        acc = __builtin_amdgcn_mfma_f32_16x16x32_bf16(af, bf, acc, 0, 0, 0);
    }
    // C/D: col(=m) = lane&15, row(=s) = quad*4 + reg
    float* up = u_ws + (size_t)(b * S + s0 + quad * 4) * M + m0 + l15;
    up[0 * M] = acc[0];
    up[1 * M] = acc[1];
    up[2 * M] = acc[2];
    up[3 * M] = acc[3];
}

// ---- kernel 3: gather + weighted sum + normalize ----
// 192 threads per (b,s). Thread owns 16B h-chunk c = t%96 and parity p = t/96;
// hot loop: 64 iterations of ONE global_load_dwordx4 + 8 cvt/FMA. Two-parity
// merge via SoA LDS at the end; denominator butterfly by wave 0 only.
__global__ __launch_bounds__(192) void gather_kernel(
    const float* __restrict__ u_ws,             // [B,S,M]
    const int*   __restrict__ lvm,              // [B,S,M]
    const float* __restrict__ mask,             // [B,S,M]
    const unsigned short* __restrict__ vt_bf,   // [VALUE_SIZE,H]
    float*       __restrict__ out)              // [B,S,H]
{
    const int bs = blockIdx.x;
    const int t  = threadIdx.x;       // 0..191
    const int p  = t / 96;            // parity: which half of m
    const int c  = t - p * 96;        // 16B chunk index, 0..95

    __shared__ float delta_s[M];
    __shared__ int   row_s[M];
    __shared__ float merge_s[8][100]; // SoA: [elem][chunk], padded
    __shared__ float dsum_s;

    const float inv_temper = rsqrtf((float)H);
    if (t < M) {
        float u  = u_ws[(size_t)bs * M + t];
        float mk = mask[(size_t)bs * M + t];
        mk = fminf(fmaxf(mk, 0.f), 1.f);
        delta_s[t] = __expf(u * inv_temper) * mk;
        row_s[t]   = lvm[(size_t)bs * M + t];
    }
    __syncthreads();

    // wave 0: denominator (consumed after the epilogue barrier)
    if (t < 64) {
        float d = delta_s[t] + delta_s[t + 64];
        #pragma unroll
        for (int off = 1; off < 64; off <<= 1) d += __shfl_xor(d, off);
        if (t == 0) dsum_s = d + 1e-10f;
    }

    float a0 = 0.f, a1 = 0.f, a2 = 0.f, a3 = 0.f;
    float a4 = 0.f, a5 = 0.f, a6 = 0.f, a7 = 0.f;

    const unsigned short* base = vt_bf + c * 8;
    #pragma unroll 8
    for (int m = p; m < M; m += 2) {
        const float pm = delta_s[m];
        ushort8v v = *(const ushort8v*)(base + (size_t)row_s[m] * H);
        a0 += pm * bf2f(v[0]);
        a1 += pm * bf2f(v[1]);
        a2 += pm * bf2f(v[2]);
        a3 += pm * bf2f(v[3]);
        a4 += pm * bf2f(v[4]);
        a5 += pm * bf2f(v[5]);
        a6 += pm * bf2f(v[6]);
        a7 += pm * bf2f(v[7]);
    }

    if (p == 1) {
        merge_s[0][c] = a0; merge_s[1][c] = a1; merge_s[2][c] = a2; merge_s[3][c] = a3;
        merge_s[4][c] = a4; merge_s[5][c] = a5; merge_s[6][c] = a6; merge_s[7][c] = a7;
    }
    __syncthreads();

    if (p == 0) {
        const float inv_d = 1.0f / dsum_s;
        float4 r0, r1;
        r0.x = (a0 + merge_s[0][c]) * inv_d;
        r0.y = (a1 + merge_s[1][c]) * inv_d;
        r0.z = (a2 + merge_s[2][c]) * inv_d;
        r0.w = (a3 + merge_s[3][c]) * inv_d;
        r1.x = (a4 + merge_s[4][c]) * inv_d;
        r1.y = (a5 + merge_s[5][c]) * inv_d;
        r1.z = (a6 + merge_s[6][c]) * inv_d;
        r1.w = (a7 + merge_s[7][c]) * inv_d;
        float4* og = (float4*)(out + (size_t)bs * H + c * 8);
        og[0] = r0;
        og[1] = r1;
    }
}

// ---- fallback: fused fp32 (only if ws too small) ----
__global__ __launch_bounds__(192) void kvmn_fp32_kernel(
    const int*   __restrict__ word_seq,
    const float* __restrict__ hidden_state,
    const int*   __restrict__ lvm,
    const float* __restrict__ mask,
    const float* __restrict__ key_table,
    const float* __restrict__ value_table,
    float*       __restrict__ out)
{
    const int bs   = blockIdx.x;
    const int b    = bs / S;
    const int t    = threadIdx.x;
    const int lane = t & 63;
    const int wave = t >> 6;

    __shared__ float4 hs4_s[C4];
    __shared__ int    wseq_s[M];
    __shared__ int    row_s[M];
    __shared__ float  mask_s[M];
    __shared__ float4 obuf[3][C4];
    __shared__ float  dsum_s3[3];

    const float4* hs_g4 = (const float4*)(hidden_state + (size_t)bs * H);
    hs4_s[t] = hs_g4[t];
    if (t < M) {
        wseq_s[t] = word_seq[b * M + t];
        row_s[t]  = lvm[(size_t)bs * M + t];
        float mk  = mask[(size_t)bs * M + t];
        mask_s[t] = fminf(fmaxf(mk, 0.f), 1.f);
    }
    __syncthreads();

    const float4 h0 = hs4_s[lane];
    const float4 h1 = hs4_s[lane + 64];
    const float4 h2 = hs4_s[lane + 128];
    const float inv_temper = rsqrtf((float)H);
    const float4* kt4 = (const float4*)key_table;
    const float4* vt4 = (const float4*)value_table;

    float4 a0 = {0.f,0.f,0.f,0.f}, a1 = {0.f,0.f,0.f,0.f}, a2 = {0.f,0.f,0.f,0.f};
    float dsum = 0.f;

    #pragma unroll 2
    for (int m = wave; m < M; m += 3) {
        const float4* kr = kt4 + (size_t)wseq_s[m] * C4;
        const float4* vr = vt4 + (size_t)row_s[m]  * C4;
        const float4 k0 = kr[lane], k1 = kr[lane+64], k2 = kr[lane+128];
        const float4 v0 = vr[lane], v1 = vr[lane+64], v2 = vr[lane+128];
        float dot = h0.x*k0.x + h0.y*k0.y + h0.z*k0.z + h0.w*k0.w
                  + h1.x*k1.x + h1.y*k1.y + h1.z*k1.z + h1.w*k1.w
                  + h2.x*k2.x + h2.y*k2.y + h2.z*k2.z + h2.w*k2.w;
        #pragma unroll
        for (int off = 1; off < 64; off <<= 1) dot += __shfl_xor(dot, off);
        const float delta = __expf(dot * inv_temper) * mask_s[m];
        dsum += delta;
        a0.x += delta*v0.x; a0.y += delta*v0.y; a0.z += delta*v0.z; a0.w += delta*v0.w;
        a1.x += delta*v1.x; a1.y += delta*v1.y; a1.z += delta*v1.z; a1.w += delta*v1.w;
        a2.x += delta*v2.x; a2.y += delta*v2.y; a2.z += delta*v2.z; a2.w += delta*v2.w;
    }
    obuf[wave][lane] = a0; obuf[wave][lane+64] = a1; obuf[wave][lane+128] = a2;
    if (lane == 0) dsum_s3[wave] = dsum;
    __syncthreads();
    const float inv_d = 1.0f / (dsum_s3[0] + dsum_s3[1] + dsum_s3[2] + 1e-10f);
    const float4 r0 = obuf[0][t], r1 = obuf[1][t], r2 = obuf[2][t];
    float4 r;
    r.x = (r0.x+r1.x+r2.x)*inv_d; r.y = (r0.y+r1.y+r2.y)*inv_d;
    r.z = (r0.z+r1.z+r2.z)*inv_d; r.w = (r0.w+r1.w+r2.w)*inv_d;
    ((float4*)(out + (size_t)bs * H))[t] = r;
}

extern "C" void kernel_launch(void* const* d_in, const int* in_sizes, int n_in,
                              void* d_out, int out_size, void* d_ws, size_t ws_size,
                              hipStream_t stream) {
    const int*   word_seq    = (const int*)  d_in[0];
    const float* hidden      = (const float*)d_in[1];
    const int*   lvm         = (const int*)  d_in[2];
    const float* mask        = (const float*)d_in[3];
    const float* key_table   = (const float*)d_in[4];
    const float* value_table = (const float*)d_in[5];
    float* out = (float*)d_out;

    if (ws_size >= WS_NEEDED) {
        unsigned short* vt_bf = (unsigned short*)d_ws;
        unsigned short* ka_bf = (unsigned short*)((char*)d_ws + VT_BYTES);
        unsigned short* hs_bf = (unsigned short*)((char*)d_ws + VT_BYTES + KA_BYTES);
        float*          u_ws  = (float*)((char*)d_ws + VT_BYTES + KA_BYTES + HS_BYTES);

        convert_kernel<<<(CONV_TOTAL + 255) / 256, 256, 0, stream>>>(
            value_table, key_table, hidden, word_seq, vt_bf, ka_bf, hs_bf);
        phaseA_kernel<<<(B * S / 16) * (M / 16) / 4, 256, 0, stream>>>(
            hs_bf, ka_bf, u_ws);
        gather_kernel<<<B * S, 192, 0, stream>>>(
            u_ws, lvm, mask, vt_bf, out);
    } else {
        kvmn_fp32_kernel<<<B * S, 192, 0, stream>>>(
            word_seq, hidden, lvm, mask, key_table, value_table, out);
    }
}